// Round 1
// baseline (862.356 us; speedup 1.0000x reference)
//
#include <hip/hip_runtime.h>

typedef __bf16 bf16;
typedef bf16 bf16x8 __attribute__((ext_vector_type(8)));
typedef float f32x4 __attribute__((ext_vector_type(4)));

#define EPS 1e-6f

// Per-wave LDS region layout (bytes):
//   feats  [16][232] bf16  @ 0      (7424)   lives until final epilogue (centered scalars)
//   vx     [480]     f32   @ 7424   (1920)   phase-A row scratch
//   Hs     [16][72]  bf16  @ 7424   (2304)   GEMM1 output (overlays dead vx)
//   gateb  [16][225] bf16  @ 7424   (7200)   GEMM2 output (overlays dead Hs)
//   srow   [16]      f32   @ 14624  (64)
// region stride 14688 B; 4 waves/block -> 58752 B -> 2 blocks/CU (8 waves/CU)

__global__ __launch_bounds__(256) void fused(
    const float* __restrict__ x,
    const float* __restrict__ b1v, const float* __restrict__ b2v,
    const float* __restrict__ aw,  const float* __restrict__ ab,
    const bf16* __restrict__ W1b,  const bf16* __restrict__ W2b,
    float* __restrict__ out)
{
    __shared__ unsigned char smem[4 * 14688];
    const int tid = threadIdx.x;
    const int wv  = tid >> 6;
    const int l   = tid & 63;
    const int q   = l >> 4;     // quad 0..3
    const int c   = l & 15;     // lane-in-16
    unsigned char* reg = smem + wv * 14688;
    bf16*  feats = (bf16*)reg;             // [16][232]
    float* vx    = (float*)(reg + 7424);   // [480]
    bf16*  Hs    = (bf16*)(reg + 7424);    // [16][72]
    bf16*  gateb = (bf16*)(reg + 7424);    // [16][225]
    float* srow  = (float*)(reg + 14624);  // [16]
    const int r0 = blockIdx.x * 64 + wv * 16;

    // ---------------- Phase A: per-row feats + norm scale ----------------
    for (int i = 0; i < 16; ++i) {
        const float* xr = x + (r0 + i) * 480;
        f32x4 a0 = *(const f32x4*)(xr + 4 * l);
        f32x4 a1 = {};
        if (l < 56) a1 = *(const f32x4*)(xr + 256 + 4 * l);
        *(f32x4*)(vx + 4 * l) = a0;
        if (l < 56) *(f32x4*)(vx + 256 + 4 * l) = a1;
        __syncthreads();

        // scalar part: mean over 128, center
        float v0 = vx[l], v1 = vx[64 + l];
        float su = v0 + v1;
        #pragma unroll
        for (int m = 1; m < 64; m <<= 1) su += __shfl_xor(su, m);
        const float mean = su * (1.0f / 128.0f);
        const float c0 = v0 - mean, c1 = v1 - mean;

        // vector part: grouped RMS (ch l: 3-group; ch 64+l (l<32): 5-group)
        const float t0 = vx[128 + 3 * l], t1 = vx[129 + 3 * l], t2 = vx[130 + 3 * l];
        const float ra = sqrtf((t0 * t0 + t1 * t1 + t2 * t2) * (1.0f / 3.0f) + EPS);
        float rb = 0.0f;
        if (l < 32) {
            const float* p = vx + 320 + 5 * l;
            float g5 = p[0]*p[0] + p[1]*p[1] + p[2]*p[2] + p[3]*p[3] + p[4]*p[4];
            rb = sqrtf(g5 * 0.2f + EPS);
        }

        bf16* fr = feats + i * 232;
        fr[l]        = (bf16)c0;
        fr[64 + l]   = (bf16)c1;
        fr[128 + l]  = (bf16)ra;
        if (l < 32) fr[192 + l] = (bf16)rb;

        float ms = c0 * c0 + c1 * c1 + ra * ra + rb * rb;
        #pragma unroll
        for (int m = 1; m < 64; m <<= 1) ms += __shfl_xor(ms, m);
        if (l == 0) srow[i] = rsqrtf(ms * (1.0f / 224.0f) + EPS);
        __syncthreads();
    }

    // ---------------- GEMM1: H = silu(s*(feats @ W1^T) + b1) ----------------
    // A-frag: lane holds A[m=c][k=q*8+j]; feats row stride 232 bf16 (29x16B)
    bf16x8 af[7];
    {
        const bf16* frow = feats + c * 232;
        #pragma unroll
        for (int ks = 0; ks < 7; ++ks)
            af[ks] = *(const bf16x8*)(frow + ks * 32 + q * 8);
    }
    #pragma unroll
    for (int t = 0; t < 4; ++t) {
        f32x4 acc = {0.f, 0.f, 0.f, 0.f};
        const int n = t * 16 + c;
        const bf16* wrow = W1b + n * 224 + q * 8;  // B[k][n] = W1[n][k]
        #pragma unroll
        for (int ks = 0; ks < 7; ++ks)
            acc = __builtin_amdgcn_mfma_f32_16x16x32_bf16(
                      af[ks], *(const bf16x8*)(wrow + ks * 32), acc, 0, 0, 0);
        float bb = 0.f;
        if (n < 56) bb = b1v[n];
        #pragma unroll
        for (int r = 0; r < 4; ++r) {
            const int row = q * 4 + r;            // C: col=c, row=q*4+r
            const float z = acc[r] * srow[row] + bb;
            float hv = 0.f;
            if (n < 56) hv = z / (1.f + __expf(-z));   // silu; zero pad cols 56..63
            Hs[row * 72 + n] = (bf16)hv;
        }
    }
    __syncthreads();

    // ---------------- GEMM2: gate = sigmoid(H @ W2^T + b2) * aff_w ----------------
    const bf16x8 ha0 = *(const bf16x8*)(Hs + c * 72 + q * 8);
    const bf16x8 ha1 = *(const bf16x8*)(Hs + c * 72 + 32 + q * 8);
    __syncthreads();   // Hs dead; gateb overlays it
    for (int t = 0; t < 14; ++t) {
        f32x4 acc = {0.f, 0.f, 0.f, 0.f};
        const int nn = t * 16 + c;
        const bf16* wrow = W2b + nn * 64 + q * 8;  // B[k][n] = W2[n][k], k-padded to 64 (zeros)
        acc = __builtin_amdgcn_mfma_f32_16x16x32_bf16(ha0, *(const bf16x8*)(wrow),      acc, 0, 0, 0);
        acc = __builtin_amdgcn_mfma_f32_16x16x32_bf16(ha1, *(const bf16x8*)(wrow + 32), acc, 0, 0, 0);
        const float bb = b2v[nn];
        const float a  = aw[nn];
        #pragma unroll
        for (int r = 0; r < 4; ++r) {
            const int row = q * 4 + r;
            const float g = a / (1.f + __expf(-(acc[r] + bb)));
            gateb[row * 225 + nn] = (bf16)g;
        }
    }
    __syncthreads();

    // ---------------- Epilogue: out = x * gate[ch_expand]; scalars = centered*gate + aff_b ----------------
    for (int i = 0; i < 16; ++i) {
        const int base = (r0 + i) * 480;
        const bf16* fr = feats + i * 232;
        const bf16* gr = gateb + i * 225;
        const float cen0 = (float)fr[l];
        const float cen1 = (float)fr[64 + l];
        out[base + l]      = cen0 * (float)gr[l]      + ab[l];
        out[base + 64 + l] = cen1 * (float)gr[64 + l] + ab[64 + l];
        #pragma unroll
        for (int k = 0; k < 6; ++k) {
            const int cc = 128 + 64 * k + l;
            if (cc < 480) {
                const int d  = cc - 128;
                const int ch = (d < 192) ? (128 + d / 3) : (192 + (d - 192) / 5);
                out[base + cc] = x[base + cc] * (float)gr[ch];
            }
        }
    }
}

// Convert W1 (56x224) -> bf16 [64][224] (rows 56..63 zero), W2 (224x56) -> bf16 [224][64] (cols 56..63 zero)
__global__ __launch_bounds__(256) void convert_w(
    const float* __restrict__ W1, const float* __restrict__ W2,
    bf16* __restrict__ W1b, bf16* __restrict__ W2b)
{
    const int t = blockIdx.x * 256 + threadIdx.x;
    if (t < 64 * 224) {
        const int n = t / 224, k = t % 224;
        W1b[t] = (n < 56) ? (bf16)W1[n * 224 + k] : (bf16)0.f;
    } else {
        const int u = t - 64 * 224;       // < 224*64
        const int n = u >> 6, kk = u & 63;
        W2b[u] = (kk < 56) ? (bf16)W2[n * 56 + kk] : (bf16)0.f;
    }
}

extern "C" void kernel_launch(void* const* d_in, const int* in_sizes, int n_in,
                              void* d_out, int out_size, void* d_ws, size_t ws_size,
                              hipStream_t stream) {
    const float* x  = (const float*)d_in[0];
    const float* W1 = (const float*)d_in[1];
    const float* b1 = (const float*)d_in[2];
    const float* W2 = (const float*)d_in[3];
    const float* b2 = (const float*)d_in[4];
    const float* aw = (const float*)d_in[5];
    const float* ab = (const float*)d_in[6];
    bf16* W1b = (bf16*)d_ws;
    bf16* W2b = W1b + 64 * 224;
    const int rows = in_sizes[0] / 480;   // 200000 = 3125 * 64
    convert_w<<<112, 256, 0, stream>>>(W1, W2, W1b, W2b);
    fused<<<rows / 64, 256, 0, stream>>>(x, b1, b2, aw, ab, W1b, W2b, (float*)d_out);
}

// Round 2
// 791.064 us; speedup vs baseline: 1.0901x; 1.0901x over previous
//
#include <hip/hip_runtime.h>

typedef __bf16 bf16;
typedef bf16 bf16x8 __attribute__((ext_vector_type(8)));
typedef float f32x4 __attribute__((ext_vector_type(4)));

#define EPS 1e-6f

// Per-wave LDS region (7488 B), barrier-free (each wave touches only its own):
//   bytes 0..7424 : feats [16][232] bf16  (phase A out, GEMM1 A-operand)
//                   then reused: Hs [16][72] bf16, then gateb [16][225] bf16
//   bytes 7424..7488 : srow [16] f32
// 4 waves * 7488 = 29952 B/block -> LDS allows 5 blocks/CU; VGPR<=128 -> 4 blocks/CU.

__global__ __launch_bounds__(256, 4) void fused(
    const float* __restrict__ x,
    const float* __restrict__ b1v, const float* __restrict__ b2v,
    const float* __restrict__ aw,  const float* __restrict__ ab,
    const bf16* __restrict__ W1b,  const bf16* __restrict__ W2b,
    float* __restrict__ out)
{
    __shared__ unsigned char smem[4 * 7488];
    const int tid = threadIdx.x;
    const int wv  = tid >> 6;
    const int l   = tid & 63;
    const int q   = l >> 4;     // quad 0..3
    const int c   = l & 15;     // lane-in-16
    unsigned char* reg = smem + wv * 7488;
    bf16*  feats = (bf16*)reg;             // [16][232]
    bf16*  Hs    = (bf16*)reg;             // [16][72]   (overlays feats after A-frag read)
    bf16*  gateb = (bf16*)reg;             // [16][225]  (overlays Hs after H-frag read)
    float* srow  = (float*)(reg + 7424);   // [16]
    const int r0 = blockIdx.x * 64 + wv * 16;

    // ---------------- Phase A: direct-layout loads, no LDS scratch, no barriers ----------------
    float cen0[16], cen1[16];
    #pragma unroll
    for (int b = 0; b < 4; ++b) {
        float v0[4], v1[4], t0[4], t1[4], t2[4], p0[4], p1[4], p2[4], p3[4], p4[4];
        #pragma unroll
        for (int j = 0; j < 4; ++j) {
            const float* xr = x + (r0 + 4 * b + j) * 480;
            v0[j] = xr[l];
            v1[j] = xr[64 + l];
            t0[j] = xr[128 + 3 * l];
            t1[j] = xr[129 + 3 * l];
            t2[j] = xr[130 + 3 * l];
            if (l < 32) {
                const float* pp = xr + 320 + 5 * l;
                p0[j] = pp[0]; p1[j] = pp[1]; p2[j] = pp[2]; p3[j] = pp[3]; p4[j] = pp[4];
            }
        }
        #pragma unroll
        for (int j = 0; j < 4; ++j) {
            const int i = 4 * b + j;
            float su = v0[j] + v1[j];
            #pragma unroll
            for (int m = 1; m < 64; m <<= 1) su += __shfl_xor(su, m);
            const float mean = su * (1.0f / 128.0f);
            const float c0 = v0[j] - mean, c1 = v1[j] - mean;
            cen0[i] = c0; cen1[i] = c1;

            const float ra = sqrtf((t0[j]*t0[j] + t1[j]*t1[j] + t2[j]*t2[j]) * (1.0f / 3.0f) + EPS);
            float rb = 0.0f;
            if (l < 32) {
                const float g5 = p0[j]*p0[j] + p1[j]*p1[j] + p2[j]*p2[j] + p3[j]*p3[j] + p4[j]*p4[j];
                rb = sqrtf(g5 * 0.2f + EPS);
            }

            bf16* fr = feats + i * 232;
            fr[l]       = (bf16)c0;
            fr[64 + l]  = (bf16)c1;
            fr[128 + l] = (bf16)ra;
            if (l < 32) fr[192 + l] = (bf16)rb;

            float ms = c0 * c0 + c1 * c1 + ra * ra + rb * rb;
            #pragma unroll
            for (int m = 1; m < 64; m <<= 1) ms += __shfl_xor(ms, m);
            if (l == 0) srow[i] = rsqrtf(ms * (1.0f / 224.0f) + EPS);
        }
    }
    __builtin_amdgcn_wave_barrier();

    // ---------------- GEMM1: H = silu(srow*(feats @ W1^T) + b1) ----------------
    bf16x8 af[7];
    {
        const bf16* frow = feats + c * 232;
        #pragma unroll
        for (int ks = 0; ks < 7; ++ks)
            af[ks] = *(const bf16x8*)(frow + ks * 32 + q * 8);
    }
    __builtin_amdgcn_wave_barrier();   // af in regs; feats region may be overwritten below
    #pragma unroll
    for (int t = 0; t < 4; ++t) {
        f32x4 acc = {0.f, 0.f, 0.f, 0.f};
        const int n = t * 16 + c;
        const bf16* wrow = W1b + n * 224 + q * 8;  // B[k][n] = W1[n][k]
        #pragma unroll
        for (int ks = 0; ks < 7; ++ks)
            acc = __builtin_amdgcn_mfma_f32_16x16x32_bf16(
                      af[ks], *(const bf16x8*)(wrow + ks * 32), acc, 0, 0, 0);
        float bb = 0.f;
        if (n < 56) bb = b1v[n];
        #pragma unroll
        for (int r = 0; r < 4; ++r) {
            const int row = q * 4 + r;            // C: col=c, row=q*4+r
            const float z = acc[r] * srow[row] + bb;
            float hv = 0.f;
            if (n < 56) hv = z / (1.f + __expf(-z));   // silu; zero pad cols 56..63
            Hs[row * 72 + n] = (bf16)hv;
        }
    }
    __builtin_amdgcn_wave_barrier();

    // ---------------- GEMM2: gate = sigmoid(H @ W2^T + b2) * aff_w ----------------
    const bf16x8 ha0 = *(const bf16x8*)(Hs + c * 72 + q * 8);
    const bf16x8 ha1 = *(const bf16x8*)(Hs + c * 72 + 32 + q * 8);
    __builtin_amdgcn_wave_barrier();   // ha in regs; Hs region may be overwritten below
    #pragma unroll
    for (int t = 0; t < 14; ++t) {
        f32x4 acc = {0.f, 0.f, 0.f, 0.f};
        const int nn = t * 16 + c;
        const bf16* wrow = W2b + nn * 64 + q * 8;  // B[k][n] = W2[n][k], k-padded to 64 (zeros)
        acc = __builtin_amdgcn_mfma_f32_16x16x32_bf16(ha0, *(const bf16x8*)(wrow),      acc, 0, 0, 0);
        acc = __builtin_amdgcn_mfma_f32_16x16x32_bf16(ha1, *(const bf16x8*)(wrow + 32), acc, 0, 0, 0);
        const float bb = b2v[nn];
        const float a  = aw[nn];
        #pragma unroll
        for (int r = 0; r < 4; ++r) {
            const int row = q * 4 + r;
            const float g = a / (1.f + __expf(-(acc[r] + bb)));
            gateb[row * 225 + nn] = (bf16)g;
        }
    }
    __builtin_amdgcn_wave_barrier();

    // ---------------- Epilogue: out = x * gate[ch_expand]; scalars = cen*gate + aff_b ----------------
    const float ab0 = ab[l], ab1 = ab[64 + l];
    #pragma unroll
    for (int i = 0; i < 16; ++i) {
        const int base = (r0 + i) * 480;
        const bf16* gr = gateb + i * 225;
        out[base + l]      = cen0[i] * (float)gr[l]      + ab0;
        out[base + 64 + l] = cen1[i] * (float)gr[64 + l] + ab1;
        #pragma unroll
        for (int k = 0; k < 6; ++k) {
            const int cc = 128 + 64 * k + l;
            if (cc < 480) {
                const int d  = cc - 128;
                const int ch = (d < 192) ? (128 + d / 3) : (192 + (d - 192) / 5);
                out[base + cc] = x[base + cc] * (float)gr[ch];
            }
        }
    }
}

// Convert W1 (56x224) -> bf16 [64][224] (rows 56..63 zero), W2 (224x56) -> bf16 [224][64] (cols 56..63 zero)
__global__ __launch_bounds__(256) void convert_w(
    const float* __restrict__ W1, const float* __restrict__ W2,
    bf16* __restrict__ W1b, bf16* __restrict__ W2b)
{
    const int t = blockIdx.x * 256 + threadIdx.x;
    if (t < 64 * 224) {
        const int n = t / 224, k = t % 224;
        W1b[t] = (n < 56) ? (bf16)W1[n * 224 + k] : (bf16)0.f;
    } else {
        const int u = t - 64 * 224;       // < 224*64
        const int n = u >> 6, kk = u & 63;
        W2b[u] = (kk < 56) ? (bf16)W2[n * 56 + kk] : (bf16)0.f;
    }
}

extern "C" void kernel_launch(void* const* d_in, const int* in_sizes, int n_in,
                              void* d_out, int out_size, void* d_ws, size_t ws_size,
                              hipStream_t stream) {
    const float* x  = (const float*)d_in[0];
    const float* W1 = (const float*)d_in[1];
    const float* b1 = (const float*)d_in[2];
    const float* W2 = (const float*)d_in[3];
    const float* b2 = (const float*)d_in[4];
    const float* aw = (const float*)d_in[5];
    const float* ab = (const float*)d_in[6];
    bf16* W1b = (bf16*)d_ws;
    bf16* W2b = W1b + 64 * 224;
    const int rows = in_sizes[0] / 480;   // 200000 = 3125 * 64
    convert_w<<<112, 256, 0, stream>>>(W1, W2, W1b, W2b);
    fused<<<rows / 64, 256, 0, stream>>>(x, b1, b2, aw, ab, W1b, W2b, (float*)d_out);
}